// Round 1
// baseline (319.584 us; speedup 1.0000x reference)
//
#include <hip/hip_runtime.h>
#include <math.h>

namespace {
constexpr int   NUM_BINS = 16;
constexpr float TAU      = 0.05f;
constexpr float EPS_SUM  = 1e-8f;
constexpr float EPS_LOG  = 1e-10f;
constexpr int   BLOCK    = 256;
constexpr int   GRID     = 2048;
}

// Sum x across the 4 lanes of a quad via DPP quad_perm (VALU pipe, no LDS).
// quad_perm ctrl: 0xB1 = (1,0,3,2) = xor 1 ; 0x4E = (2,3,0,1) = xor 2.
__device__ inline float quad_sum(float x) {
    int a = __builtin_amdgcn_mov_dpp(__float_as_int(x), 0xB1, 0xF, 0xF, true);
    x += __int_as_float(a);
    a = __builtin_amdgcn_mov_dpp(__float_as_int(x), 0x4E, 0xF, 0xF, true);
    x += __int_as_float(a);
    return x;
}

// Hardware transcendentals: v_log_f32 is log2 (~1 ulp), v_rcp_f32 ~1 ulp.
// Used ONLY on smooth paths (entropy / info-gain / EMA), never on the bin
// decision, which stays bit-identical to the previously verified kernel
// (libm expf + exact IEEE divide) to avoid bin flips at sig*15 boundaries.
__device__ inline float fast_log2(float x) { return __log2f(x); }
__device__ inline float fast_rcp(float x)  { return __builtin_amdgcn_rcpf(x); }

// Kernel 1: 4 lanes cooperate on one belief row. All global accesses are
// lane-linear (fully coalesced): belief float4/lane, nb 2x float2/lane.
__global__ __launch_bounds__(BLOCK) void ev_main(
    const float* __restrict__ obs,          // (8, dim)
    const float* __restrict__ belief,       // (dim, 16)
    float* __restrict__ out_info,           // (dim,)
    float* __restrict__ out_Hprior,         // (dim,)
    float* __restrict__ out_Hpost,          // (dim,)
    float* __restrict__ out_newbelief,      // (dim,16) slice, 8B-aligned only
    float* __restrict__ ws_partials,        // (GRID,)
    int dim)
{
    const int tid    = blockIdx.x * BLOCK + threadIdx.x;
    const int stride = BLOCK * GRID;
    const int W      = dim * 4;             // total quarter-row work items
    float local_sum = 0.0f;                 // accumulates 4x ig per row

    const float4* belief4 = reinterpret_cast<const float4*>(belief);
    float2* nb2 = reinterpret_cast<float2*>(out_newbelief);

#pragma unroll 4
    for (int f = tid; f < W; f += stride) {
        const int r = f >> 2;               // row (uniform within quad)
        const int m = f & 3;                // lane's chunk within row

        // ---- coalesced loads ----
        float4 c4 = belief4[f];             // 16B/lane, lane-linear
        float cs = (c4.x + c4.y) + (c4.z + c4.w);
        // each lane reads 2 of the 8 observation rows for this column
        float os = obs[(size_t)(2 * m) * dim + r]
                 + obs[(size_t)(2 * m + 1) * dim + r];

        // ---- quad reductions (DPP, VALU pipe) ----
        cs = quad_sum(cs);                  // row count-sum
        os = quad_sum(os);                  // sum of 8 obs values
        float om = os * 0.125f;

        // Bin decision: EXACT libm expf + exact divide (bit-identical to the
        // verified kernel; discontinuous consumer, do not approximate).
        float sig = 1.0f / (1.0f + expf(-om));
        int bin = (int)(sig * 15.0f);
        bin = bin < 0 ? 0 : (bin > 15 ? 15 : bin);

        // Smooth path: hardware rcp is plenty accurate (~1 ulp).
        float inv_prior = fast_rcp(fmaxf(cs, EPS_SUM));
        float inv_post  = fast_rcp(fmaxf(cs + 1.0f, EPS_SUM));

        float Hpr = 0.0f, Hpo = 0.0f, ig = 0.0f;
        float cc[4] = {c4.x, c4.y, c4.z, c4.w};
        float nb[4];
        const int j0 = m * 4;
#pragma unroll
        for (int e = 0; e < 4; ++e) {
            float cj = cc[e];
            bool hit = (j0 + e == bin);
            float oh = hit ? 1.0f : 0.0f;
            float p  = cj * inv_prior;
            float pp = (cj + oh) * inv_post;
            float lp  = fast_log2(p  + EPS_LOG);   // v_log_f32
            float lpp = fast_log2(pp + EPS_LOG);   // v_log_f32
            Hpr -= p  * lp;
            Hpo -= pp * lpp;
            ig  += pp * (lpp - lp);
            nb[e] = fmaxf(fmaf(cj, 1.0f - TAU, hit ? TAU : 0.0f), 0.01f);
        }
        Hpr = quad_sum(Hpr);
        Hpo = quad_sum(Hpo);
        ig  = fmaxf(quad_sum(ig), 0.0f);
        local_sum += ig;                    // counted 4x; divided out later

        if (m == 0) {
            out_info[r]   = ig;
            out_Hprior[r] = Hpr;
            out_Hpost[r]  = Hpo;
        }

        // ---- coalesced nb store (8B-aligned output slice -> float2) ----
        nb2[(size_t)f * 2]     = make_float2(nb[0], nb[1]);
        nb2[(size_t)f * 2 + 1] = make_float2(nb[2], nb[3]);
    }

    // ---- block reduction of info_gain partials ----
    __shared__ float sdata[BLOCK];
    sdata[threadIdx.x] = local_sum;
    __syncthreads();
#pragma unroll
    for (int off = BLOCK / 2; off > 0; off >>= 1) {
        if (threadIdx.x < off) sdata[threadIdx.x] += sdata[threadIdx.x + off];
        __syncthreads();
    }
    if (threadIdx.x == 0) ws_partials[blockIdx.x] = sdata[0];
}

// Kernel 2: reduce GRID partials -> mean_info_gain + epistemic_value.
__global__ __launch_bounds__(BLOCK) void ev_finalize(
    const float* __restrict__ ws_partials,
    float* __restrict__ out_mean,
    float* __restrict__ out_epi,
    int n_partials, float inv_cnt)
{
    float s = 0.0f;
    for (int i = threadIdx.x; i < n_partials; i += BLOCK) s += ws_partials[i];
    __shared__ float sdata[BLOCK];
    sdata[threadIdx.x] = s;
    __syncthreads();
#pragma unroll
    for (int off = BLOCK / 2; off > 0; off >>= 1) {
        if (threadIdx.x < off) sdata[threadIdx.x] += sdata[threadIdx.x + off];
        __syncthreads();
    }
    if (threadIdx.x == 0) {
        float mean = sdata[0] * inv_cnt;
        *out_mean = mean;
        *out_epi  = 1.0f / (1.0f + expf(-(mean * 50.0f - 1.0f)));
    }
}

extern "C" void kernel_launch(void* const* d_in, const int* in_sizes, int n_in,
                              void* d_out, int out_size, void* d_ws, size_t ws_size,
                              hipStream_t stream)
{
    const float* obs    = (const float*)d_in[0];   // (8, dim) fp32
    const float* belief = (const float*)d_in[1];   // (dim, 16) fp32
    const int dim = in_sizes[0] / 8;

    // Output layout (flat, return order):
    // [0, dim) info | [dim] mean | [dim+1, 2dim+1) H_prior |
    // [2dim+1, 3dim+1) H_post | [3dim+1] epi | [3dim+2, ...) new_belief
    float* o             = (float*)d_out;
    float* out_info      = o;
    float* out_mean      = o + dim;
    float* out_Hprior    = o + dim + 1;
    float* out_Hpost     = o + 2 * (size_t)dim + 1;
    float* out_epi       = o + 3 * (size_t)dim + 1;
    float* out_newbelief = o + 3 * (size_t)dim + 2;

    float* partials = (float*)d_ws;   // GRID floats; fully overwritten each call

    ev_main<<<GRID, BLOCK, 0, stream>>>(obs, belief, out_info, out_Hprior,
                                        out_Hpost, out_newbelief, partials, dim);
    // local_sum counted each row 4x (once per quad lane) -> divide by 4*dim
    ev_finalize<<<1, BLOCK, 0, stream>>>(partials, out_mean, out_epi, GRID,
                                         1.0f / (4.0f * (float)dim));
}

// Round 2
// 318.303 us; speedup vs baseline: 1.0040x; 1.0040x over previous
//
#include <hip/hip_runtime.h>
#include <math.h>

namespace {
constexpr float TAU      = 0.05f;
constexpr float EPS_SUM  = 1e-8f;
constexpr float EPS_LOG  = 1e-10f;
constexpr int   BLOCK    = 256;
constexpr int   GRID     = 2048;
}

// Sum x across the 4 lanes of a quad via DPP quad_perm (VALU pipe, no LDS).
// quad_perm ctrl: 0xB1 = (1,0,3,2) = xor 1 ; 0x4E = (2,3,0,1) = xor 2.
__device__ inline float quad_sum(float x) {
    int a = __builtin_amdgcn_mov_dpp(__float_as_int(x), 0xB1, 0xF, 0xF, true);
    x += __int_as_float(a);
    a = __builtin_amdgcn_mov_dpp(__float_as_int(x), 0x4E, 0xF, 0xF, true);
    x += __int_as_float(a);
    return x;
}

// Hardware transcendentals: v_log_f32 is log2 (~1 ulp), v_rcp_f32 ~1 ulp.
// Smooth paths only; the bin decision keeps libm expf + exact divide
// (bit-identical to the verified kernel) to avoid bin flips.
__device__ inline float fast_log2(float x) { return __log2f(x); }
__device__ inline float fast_rcp(float x)  { return __builtin_amdgcn_rcpf(x); }

// One quarter-row work item (4 lanes of a quad cooperate on one belief row).
__device__ __forceinline__ void process_item(
    int f, float4 c4, float oa, float ob,
    float* __restrict__ out_info, float* __restrict__ out_Hprior,
    float* __restrict__ out_Hpost, float2* __restrict__ nb2,
    float& local_sum)
{
    const int r = f >> 2;
    const int m = f & 3;

    float cs = (c4.x + c4.y) + (c4.z + c4.w);
    float os = oa + ob;
    cs = quad_sum(cs);                  // row count-sum
    os = quad_sum(os);                  // sum of 8 obs values
    float om = os * 0.125f;

    // Bin decision: EXACT libm expf + exact divide (discontinuous consumer).
    float sig = 1.0f / (1.0f + expf(-om));
    int bin = (int)(sig * 15.0f);
    bin = bin < 0 ? 0 : (bin > 15 ? 15 : bin);

    float inv_prior = fast_rcp(fmaxf(cs, EPS_SUM));
    float inv_post  = fast_rcp(fmaxf(cs + 1.0f, EPS_SUM));

    float Hpr = 0.0f, Hpo = 0.0f, ig = 0.0f;
    float cc[4] = {c4.x, c4.y, c4.z, c4.w};
    float nb[4];
    const int j0 = m * 4;
#pragma unroll
    for (int e = 0; e < 4; ++e) {
        float cj = cc[e];
        bool hit = (j0 + e == bin);
        float oh = hit ? 1.0f : 0.0f;
        float p  = cj * inv_prior;
        float pp = (cj + oh) * inv_post;
        float lp  = fast_log2(p  + EPS_LOG);   // v_log_f32
        float lpp = fast_log2(pp + EPS_LOG);   // v_log_f32
        Hpr -= p  * lp;
        Hpo -= pp * lpp;
        ig  += pp * (lpp - lp);
        nb[e] = fmaxf(fmaf(cj, 1.0f - TAU, hit ? TAU : 0.0f), 0.01f);
    }
    Hpr = quad_sum(Hpr);
    Hpo = quad_sum(Hpo);
    ig  = fmaxf(quad_sum(ig), 0.0f);
    local_sum += ig;                    // counted 4x; divided out later

    if (m == 0) {
        out_info[r]   = ig;
        out_Hprior[r] = Hpr;
        out_Hpost[r]  = Hpo;
    }
    // coalesced nb store (8B-aligned output slice -> float2)
    nb2[(size_t)f * 2]     = make_float2(nb[0], nb[1]);
    nb2[(size_t)f * 2 + 1] = make_float2(nb[2], nb[3]);
}

// Kernel 1: depth-2 software pipeline, 2 items per trip -> 6 load
// instructions in flight while the previous pair computes. Loads can't
// alias the stores (__restrict__), so the prefetches stay hoisted.
__global__ __launch_bounds__(BLOCK) void ev_main(
    const float* __restrict__ obs,          // (8, dim)
    const float* __restrict__ belief,       // (dim, 16)
    float* __restrict__ out_info,           // (dim,)
    float* __restrict__ out_Hprior,         // (dim,)
    float* __restrict__ out_Hpost,          // (dim,)
    float* __restrict__ out_newbelief,      // (dim,16) slice, 8B-aligned only
    float* __restrict__ ws_partials,        // (GRID,)
    int dim)
{
    const int tid    = blockIdx.x * BLOCK + threadIdx.x;
    const int stride = BLOCK * GRID;
    const int W      = dim * 4;             // total quarter-row work items
    const int step2  = 2 * stride;
    const int Wbulk  = W - (W % step2);     // bulk region: pairs need no guards
    float local_sum = 0.0f;

    const float4* belief4 = reinterpret_cast<const float4*>(belief);
    float2* nb2 = reinterpret_cast<float2*>(out_newbelief);

    int f = tid;
    float4 A0, A1;
    float oa0, ob0, oa1, ob1;
    if (f < Wbulk) {
        const int f1 = f + stride;
        A0 = belief4[f];
        { int r = f  >> 2, m = f  & 3;
          oa0 = obs[(size_t)(2 * m) * dim + r];
          ob0 = obs[(size_t)(2 * m + 1) * dim + r]; }
        A1 = belief4[f1];
        { int r = f1 >> 2, m = f1 & 3;
          oa1 = obs[(size_t)(2 * m) * dim + r];
          ob1 = obs[(size_t)(2 * m + 1) * dim + r]; }
    }

    for (; f < Wbulk; f += step2) {
        // ---- prefetch next pair (clamped at the boundary; redundant reload
        //      of current f on the last trip is harmless) ----
        const int fp   = f + step2;
        const bool more = (fp < Wbulk);          // uniform across the wave
        const int g0 = more ? fp : f;
        const int g1 = more ? fp + stride : f;
        float4 P0 = belief4[g0];
        float4 P1 = belief4[g1];
        float pa0, pb0, pa1, pb1;
        { int r = g0 >> 2, m = g0 & 3;
          pa0 = obs[(size_t)(2 * m) * dim + r];
          pb0 = obs[(size_t)(2 * m + 1) * dim + r]; }
        { int r = g1 >> 2, m = g1 & 3;
          pa1 = obs[(size_t)(2 * m) * dim + r];
          pb1 = obs[(size_t)(2 * m + 1) * dim + r]; }

        // ---- compute current pair while prefetches are in flight ----
        process_item(f,          A0, oa0, ob0,
                     out_info, out_Hprior, out_Hpost, nb2, local_sum);
        process_item(f + stride, A1, oa1, ob1,
                     out_info, out_Hprior, out_Hpost, nb2, local_sum);

        // ---- rotate pipeline ----
        A0 = P0; oa0 = pa0; ob0 = pb0;
        A1 = P1; oa1 = pa1; ob1 = pb1;
    }

    // tail (never taken when W % step2 == 0, e.g. the bench shape)
    for (; f < W; f += stride) {
        float4 c4 = belief4[f];
        float oa, ob;
        { int r = f >> 2, m = f & 3;
          oa = obs[(size_t)(2 * m) * dim + r];
          ob = obs[(size_t)(2 * m + 1) * dim + r]; }
        process_item(f, c4, oa, ob,
                     out_info, out_Hprior, out_Hpost, nb2, local_sum);
    }

    // ---- block reduction of info_gain partials ----
    __shared__ float sdata[BLOCK];
    sdata[threadIdx.x] = local_sum;
    __syncthreads();
#pragma unroll
    for (int off = BLOCK / 2; off > 0; off >>= 1) {
        if (threadIdx.x < off) sdata[threadIdx.x] += sdata[threadIdx.x + off];
        __syncthreads();
    }
    if (threadIdx.x == 0) ws_partials[blockIdx.x] = sdata[0];
}

// Kernel 2: reduce GRID partials -> mean_info_gain + epistemic_value.
__global__ __launch_bounds__(BLOCK) void ev_finalize(
    const float* __restrict__ ws_partials,
    float* __restrict__ out_mean,
    float* __restrict__ out_epi,
    int n_partials, float inv_cnt)
{
    float s = 0.0f;
    for (int i = threadIdx.x; i < n_partials; i += BLOCK) s += ws_partials[i];
    __shared__ float sdata[BLOCK];
    sdata[threadIdx.x] = s;
    __syncthreads();
#pragma unroll
    for (int off = BLOCK / 2; off > 0; off >>= 1) {
        if (threadIdx.x < off) sdata[threadIdx.x] += sdata[threadIdx.x + off];
        __syncthreads();
    }
    if (threadIdx.x == 0) {
        float mean = sdata[0] * inv_cnt;
        *out_mean = mean;
        *out_epi  = 1.0f / (1.0f + expf(-(mean * 50.0f - 1.0f)));
    }
}

extern "C" void kernel_launch(void* const* d_in, const int* in_sizes, int n_in,
                              void* d_out, int out_size, void* d_ws, size_t ws_size,
                              hipStream_t stream)
{
    const float* obs    = (const float*)d_in[0];   // (8, dim) fp32
    const float* belief = (const float*)d_in[1];   // (dim, 16) fp32
    const int dim = in_sizes[0] / 8;

    // Output layout (flat, return order):
    // [0, dim) info | [dim] mean | [dim+1, 2dim+1) H_prior |
    // [2dim+1, 3dim+1) H_post | [3dim+1] epi | [3dim+2, ...) new_belief
    float* o             = (float*)d_out;
    float* out_info      = o;
    float* out_mean      = o + dim;
    float* out_Hprior    = o + dim + 1;
    float* out_Hpost     = o + 2 * (size_t)dim + 1;
    float* out_epi       = o + 3 * (size_t)dim + 1;
    float* out_newbelief = o + 3 * (size_t)dim + 2;

    float* partials = (float*)d_ws;   // GRID floats; fully overwritten each call

    ev_main<<<GRID, BLOCK, 0, stream>>>(obs, belief, out_info, out_Hprior,
                                        out_Hpost, out_newbelief, partials, dim);
    // local_sum counted each row 4x (once per quad lane) -> divide by 4*dim
    ev_finalize<<<1, BLOCK, 0, stream>>>(partials, out_mean, out_epi, GRID,
                                         1.0f / (4.0f * (float)dim));
}

// Round 3
// 313.189 us; speedup vs baseline: 1.0204x; 1.0163x over previous
//
#include <hip/hip_runtime.h>
#include <math.h>

namespace {
constexpr float TAU      = 0.05f;
constexpr float EPS_SUM  = 1e-8f;
constexpr float EPS_LOG  = 1e-10f;
constexpr int   BLOCK    = 256;
constexpr int   GRID     = 2048;
}

// Sum x across the 4 lanes of a quad via DPP quad_perm (VALU pipe, no LDS).
// quad_perm ctrl: 0xB1 = (1,0,3,2) = xor 1 ; 0x4E = (2,3,0,1) = xor 2.
__device__ inline float quad_sum(float x) {
    int a = __builtin_amdgcn_mov_dpp(__float_as_int(x), 0xB1, 0xF, 0xF, true);
    x += __int_as_float(a);
    a = __builtin_amdgcn_mov_dpp(__float_as_int(x), 0x4E, 0xF, 0xF, true);
    x += __int_as_float(a);
    return x;
}

// Hardware transcendentals: v_log_f32 is log2 (~1 ulp), v_rcp_f32 ~1 ulp.
// Smooth paths only; the bin decision keeps libm expf + exact divide.
__device__ inline float fast_log2(float x) { return __log2f(x); }
__device__ inline float fast_rcp(float x)  { return __builtin_amdgcn_rcpf(x); }

// ---------------------------------------------------------------------------
// Kernel A: bin pre-pass. Reads obs (8,dim) fully coalesced (float4/lane),
// computes the bin index per row with arithmetic BIT-IDENTICAL to the fused
// kernel's quad_sum tree: os = ((o0+o1)+(o2+o3)) + ((o4+o5)+(o6+o7)).
// Writes bins as floats into workspace.
// ---------------------------------------------------------------------------
__device__ __forceinline__ float bin_from8(float o0, float o1, float o2, float o3,
                                           float o4, float o5, float o6, float o7) {
    float x0 = o0 + o1, x1 = o2 + o3, x2 = o4 + o5, x3 = o6 + o7;
    float os = (x0 + x1) + (x2 + x3);
    float om = os * 0.125f;
    float sig = 1.0f / (1.0f + expf(-om));   // exact libm path, as before
    int bin = (int)(sig * 15.0f);
    bin = bin < 0 ? 0 : (bin > 15 ? 15 : bin);
    return (float)bin;
}

__global__ __launch_bounds__(BLOCK) void ev_bins(
    const float* __restrict__ obs,      // (8, dim)
    float* __restrict__ bins,           // (dim,) float-coded bin index
    int dim)
{
    const int gid = blockIdx.x * BLOCK + threadIdx.x;
    const int gstride = BLOCK * gridDim.x;
    const int total4 = dim >> 2;
    const size_t d4 = (size_t)total4;
    const float4* obs4 = reinterpret_cast<const float4*>(obs);
    float4* bins4 = reinterpret_cast<float4*>(bins);

    for (int c = gid; c < total4; c += gstride) {
        float4 r0 = obs4[0 * d4 + c];
        float4 r1 = obs4[1 * d4 + c];
        float4 r2 = obs4[2 * d4 + c];
        float4 r3 = obs4[3 * d4 + c];
        float4 r4 = obs4[4 * d4 + c];
        float4 r5 = obs4[5 * d4 + c];
        float4 r6 = obs4[6 * d4 + c];
        float4 r7 = obs4[7 * d4 + c];
        float4 b;
        b.x = bin_from8(r0.x, r1.x, r2.x, r3.x, r4.x, r5.x, r6.x, r7.x);
        b.y = bin_from8(r0.y, r1.y, r2.y, r3.y, r4.y, r5.y, r6.y, r7.y);
        b.z = bin_from8(r0.z, r1.z, r2.z, r3.z, r4.z, r5.z, r6.z, r7.z);
        b.w = bin_from8(r0.w, r1.w, r2.w, r3.w, r4.w, r5.w, r6.w, r7.w);
        bins4[c] = b;
    }
    // scalar tail for dim % 4 != 0 (empty for the bench shape)
    for (int c = total4 * 4 + gid; c < dim; c += gstride) {
        bins[c] = bin_from8(obs[0 * (size_t)dim + c], obs[1 * (size_t)dim + c],
                            obs[2 * (size_t)dim + c], obs[3 * (size_t)dim + c],
                            obs[4 * (size_t)dim + c], obs[5 * (size_t)dim + c],
                            obs[6 * (size_t)dim + c], obs[7 * (size_t)dim + c]);
    }
}

// ---------------------------------------------------------------------------
// Shared per-item body for the belief pass (bin already known).
// ---------------------------------------------------------------------------
__device__ __forceinline__ void process_item(
    int f, float4 c4, int bin,
    float* __restrict__ out_info, float* __restrict__ out_Hprior,
    float* __restrict__ out_Hpost, float2* __restrict__ nb2,
    float& local_sum)
{
    const int r = f >> 2;
    const int m = f & 3;

    float cs = quad_sum((c4.x + c4.y) + (c4.z + c4.w));   // row count-sum

    float inv_prior = fast_rcp(fmaxf(cs, EPS_SUM));
    float inv_post  = fast_rcp(fmaxf(cs + 1.0f, EPS_SUM));

    float Hpr = 0.0f, Hpo = 0.0f, ig = 0.0f;
    float cc[4] = {c4.x, c4.y, c4.z, c4.w};
    float nb[4];
    const int j0 = m * 4;
#pragma unroll
    for (int e = 0; e < 4; ++e) {
        float cj = cc[e];
        bool hit = (j0 + e == bin);
        float oh = hit ? 1.0f : 0.0f;
        float p  = cj * inv_prior;
        float pp = (cj + oh) * inv_post;
        float lp  = fast_log2(p  + EPS_LOG);   // v_log_f32
        float lpp = fast_log2(pp + EPS_LOG);   // v_log_f32
        Hpr -= p  * lp;
        Hpo -= pp * lpp;
        ig  += pp * (lpp - lp);
        nb[e] = fmaxf(fmaf(cj, 1.0f - TAU, hit ? TAU : 0.0f), 0.01f);
    }
    Hpr = quad_sum(Hpr);
    Hpo = quad_sum(Hpo);
    ig  = fmaxf(quad_sum(ig), 0.0f);
    local_sum += ig;                    // counted 4x; divided out later

    if (m == 0) {
        out_info[r]   = ig;
        out_Hprior[r] = Hpr;
        out_Hpost[r]  = Hpo;
    }
    nb2[(size_t)f * 2]     = make_float2(nb[0], nb[1]);
    nb2[(size_t)f * 2 + 1] = make_float2(nb[2], nb[3]);
}

// ---------------------------------------------------------------------------
// Kernel B: belief pass, depth-2 pipeline (2 items/trip, 4 loads in flight).
// sched_barrier(0) pins the prefetch loads ABOVE the compute — the round-2
// version let the scheduler sink them (VGPR stayed 24, no pipeline).
// ---------------------------------------------------------------------------
__global__ __launch_bounds__(BLOCK) void ev_main(
    const float* __restrict__ belief,       // (dim, 16)
    const float* __restrict__ binsf,        // (dim,) from ev_bins (workspace)
    float* __restrict__ out_info,           // (dim,)
    float* __restrict__ out_Hprior,         // (dim,)
    float* __restrict__ out_Hpost,          // (dim,)
    float* __restrict__ out_newbelief,      // (dim,16) slice, 8B-aligned only
    float* __restrict__ ws_partials,        // (GRID,)
    int dim)
{
    const int tid    = blockIdx.x * BLOCK + threadIdx.x;
    const int stride = BLOCK * GRID;
    const int W      = dim * 4;             // quarter-row work items
    const int step2  = 2 * stride;
    const int Wbulk  = W - (W % step2);
    float local_sum = 0.0f;

    const float4* belief4 = reinterpret_cast<const float4*>(belief);
    float2* nb2 = reinterpret_cast<float2*>(out_newbelief);

    int f = tid;
    float4 A0, A1;
    float b0, b1;
    if (f < Wbulk) {
        A0 = belief4[f];
        b0 = binsf[f >> 2];
        A1 = belief4[f + stride];
        b1 = binsf[(f + stride) >> 2];
    }

    for (; f < Wbulk; f += step2) {
        // ---- prefetch next pair (clamped; redundant reload on last trip) ----
        const int fp = f + step2;
        const bool more = (fp < Wbulk);          // uniform across the wave
        const int g0 = more ? fp : f;
        const int g1 = more ? fp + stride : f;
        float4 P0 = belief4[g0];
        float  p0 = binsf[g0 >> 2];
        float4 P1 = belief4[g1];
        float  p1 = binsf[g1 >> 2];

        // Nothing may cross this point: prefetches stay issued above compute.
        __builtin_amdgcn_sched_barrier(0);

        process_item(f,          A0, (int)b0,
                     out_info, out_Hprior, out_Hpost, nb2, local_sum);
        process_item(f + stride, A1, (int)b1,
                     out_info, out_Hprior, out_Hpost, nb2, local_sum);

        A0 = P0; b0 = p0;
        A1 = P1; b1 = p1;
    }

    // tail (empty when W % step2 == 0, e.g. the bench shape)
    for (; f < W; f += stride) {
        float4 c4 = belief4[f];
        int bin = (int)binsf[f >> 2];
        process_item(f, c4, bin,
                     out_info, out_Hprior, out_Hpost, nb2, local_sum);
    }

    __shared__ float sdata[BLOCK];
    sdata[threadIdx.x] = local_sum;
    __syncthreads();
#pragma unroll
    for (int off = BLOCK / 2; off > 0; off >>= 1) {
        if (threadIdx.x < off) sdata[threadIdx.x] += sdata[threadIdx.x + off];
        __syncthreads();
    }
    if (threadIdx.x == 0) ws_partials[blockIdx.x] = sdata[0];
}

// ---------------------------------------------------------------------------
// Fallback: fused kernel (round-1 structure, known-passing) for the case the
// workspace is too small to hold the bins array.
// ---------------------------------------------------------------------------
__global__ __launch_bounds__(BLOCK) void ev_fused(
    const float* __restrict__ obs,
    const float* __restrict__ belief,
    float* __restrict__ out_info,
    float* __restrict__ out_Hprior,
    float* __restrict__ out_Hpost,
    float* __restrict__ out_newbelief,
    float* __restrict__ ws_partials,
    int dim)
{
    const int tid    = blockIdx.x * BLOCK + threadIdx.x;
    const int stride = BLOCK * GRID;
    const int W      = dim * 4;
    float local_sum = 0.0f;

    const float4* belief4 = reinterpret_cast<const float4*>(belief);
    float2* nb2 = reinterpret_cast<float2*>(out_newbelief);

    for (int f = tid; f < W; f += stride) {
        const int r = f >> 2;
        const int m = f & 3;
        float4 c4 = belief4[f];
        float oa = obs[(size_t)(2 * m) * dim + r];
        float ob = obs[(size_t)(2 * m + 1) * dim + r];
        float os = quad_sum(oa + ob);
        float om = os * 0.125f;
        float sig = 1.0f / (1.0f + expf(-om));
        int bin = (int)(sig * 15.0f);
        bin = bin < 0 ? 0 : (bin > 15 ? 15 : bin);
        process_item(f, c4, bin,
                     out_info, out_Hprior, out_Hpost, nb2, local_sum);
    }

    __shared__ float sdata[BLOCK];
    sdata[threadIdx.x] = local_sum;
    __syncthreads();
#pragma unroll
    for (int off = BLOCK / 2; off > 0; off >>= 1) {
        if (threadIdx.x < off) sdata[threadIdx.x] += sdata[threadIdx.x + off];
        __syncthreads();
    }
    if (threadIdx.x == 0) ws_partials[blockIdx.x] = sdata[0];
}

// Kernel 2: reduce GRID partials -> mean_info_gain + epistemic_value.
__global__ __launch_bounds__(BLOCK) void ev_finalize(
    const float* __restrict__ ws_partials,
    float* __restrict__ out_mean,
    float* __restrict__ out_epi,
    int n_partials, float inv_cnt)
{
    float s = 0.0f;
    for (int i = threadIdx.x; i < n_partials; i += BLOCK) s += ws_partials[i];
    __shared__ float sdata[BLOCK];
    sdata[threadIdx.x] = s;
    __syncthreads();
#pragma unroll
    for (int off = BLOCK / 2; off > 0; off >>= 1) {
        if (threadIdx.x < off) sdata[threadIdx.x] += sdata[threadIdx.x + off];
        __syncthreads();
    }
    if (threadIdx.x == 0) {
        float mean = sdata[0] * inv_cnt;
        *out_mean = mean;
        *out_epi  = 1.0f / (1.0f + expf(-(mean * 50.0f - 1.0f)));
    }
}

extern "C" void kernel_launch(void* const* d_in, const int* in_sizes, int n_in,
                              void* d_out, int out_size, void* d_ws, size_t ws_size,
                              hipStream_t stream)
{
    const float* obs    = (const float*)d_in[0];   // (8, dim) fp32
    const float* belief = (const float*)d_in[1];   // (dim, 16) fp32
    const int dim = in_sizes[0] / 8;

    // Output layout (flat, return order):
    // [0, dim) info | [dim] mean | [dim+1, 2dim+1) H_prior |
    // [2dim+1, 3dim+1) H_post | [3dim+1] epi | [3dim+2, ...) new_belief
    float* o             = (float*)d_out;
    float* out_info      = o;
    float* out_mean      = o + dim;
    float* out_Hprior    = o + dim + 1;
    float* out_Hpost     = o + 2 * (size_t)dim + 1;
    float* out_epi       = o + 3 * (size_t)dim + 1;
    float* out_newbelief = o + 3 * (size_t)dim + 2;

    float* partials = (float*)d_ws;                 // GRID floats
    float* bins     = (float*)d_ws + GRID;          // dim floats (16B-aligned:
                                                    // GRID*4 = 8192 bytes)
    const size_t ws_needed = sizeof(float) * ((size_t)GRID + (size_t)dim);

    if (ws_size >= ws_needed) {
        ev_bins<<<GRID, BLOCK, 0, stream>>>(obs, bins, dim);
        ev_main<<<GRID, BLOCK, 0, stream>>>(belief, bins, out_info, out_Hprior,
                                            out_Hpost, out_newbelief, partials,
                                            dim);
    } else {
        ev_fused<<<GRID, BLOCK, 0, stream>>>(obs, belief, out_info, out_Hprior,
                                             out_Hpost, out_newbelief, partials,
                                             dim);
    }
    // local_sum counted each row 4x (once per quad lane) -> divide by 4*dim
    ev_finalize<<<1, BLOCK, 0, stream>>>(partials, out_mean, out_epi, GRID,
                                         1.0f / (4.0f * (float)dim));
}